// Round 1
// baseline (280.882 us; speedup 1.0000x reference)
//
#include <hip/hip_runtime.h>
#include <cstdint>
#include <cstddef>
#include <cmath>

// RelPosMHA: x[32,512,512] f32 -> QKV proj -> rel-pos-bias attention -> out proj.
// Design:
//  - k_cvt: f32 -> bf16 for x and Wq/Wk/Wv/Wo (one pass, float4 loads).
//  - k_gemm_qkv: m97-style 128x128 bf16 MFMA GEMM (BK=32, global_load_lds w=16,
//    XOR slot swizzle). Fused over 12 n-blocks: sel 0=Q (scaled 1/8), 1=K, 2=V
//    (V written TRANSPOSED [b,h,dk,t] so attention PV B-frags are contiguous).
//  - k_attn: flash attention, 4 waves x 16 q-rows per block, KBLK=64, online
//    softmax; rel_table column h staged in LDS; P transposed via per-wave LDS.
//  - k_gemm_out: same GEMM, f32 epilogue + bias -> d_out.

typedef __attribute__((ext_vector_type(8))) short bf16x8;
typedef __attribute__((ext_vector_type(4))) float f32x4;
typedef __attribute__((ext_vector_type(4))) unsigned short u16x4;

typedef __attribute__((address_space(3))) unsigned int lds_u32;
typedef const __attribute__((address_space(1))) unsigned int glb_u32;

__device__ __forceinline__ unsigned short f2b(float f) {
  unsigned int u = __builtin_bit_cast(unsigned int, f);
  u += 0x7fffu + ((u >> 16) & 1u);   // RNE (no NaN inputs in this pipeline)
  return (unsigned short)(u >> 16);
}

__device__ __forceinline__ void gll16(const void* g, void* l) {
  __builtin_amdgcn_global_load_lds((glb_u32*)g, (lds_u32*)l, 16, 0, 0);
}

// ---------------- convert f32 -> bf16 (x + 4 weights) ----------------
__global__ __launch_bounds__(256) void k_cvt(
    const float* __restrict__ x,
    const float* __restrict__ w0, const float* __restrict__ w1,
    const float* __restrict__ w2, const float* __restrict__ w3,
    short* __restrict__ xb, short* __restrict__ wb)
{
  size_t i = (size_t)blockIdx.x * 256 + threadIdx.x;
  size_t e = i * 4;
  const float* s;
  short* d;
  if (e < (size_t)8388608) { s = x + e; d = xb + e; }
  else {
    size_t r = e - 8388608;
    int ws = (int)(r >> 18);
    const float* wp = ws == 0 ? w0 : ws == 1 ? w1 : ws == 2 ? w2 : w3;
    s = wp + (r & 262143);
    d = wb + r;
  }
  f32x4 v = *(const f32x4*)s;
  u16x4 o;
  o.x = f2b(v.x); o.y = f2b(v.y); o.z = f2b(v.z); o.w = f2b(v.w);
  *(u16x4*)d = o;
}

// ---------------- shared GEMM mainloop: C[128x128] += A[128xK] * B[128xK]^T ----
// A, B row-major with K=512 contiguous. BK=32 (64B rows, 4x16B slots).
// LDS slot XOR-swizzle ((row>>1)&3) so each 16-lane ds_read_b128 batch covers
// 8 distinct bank-quads (2 accesses/bank = floor) instead of 2 quads (4x).
__device__ __forceinline__ void gemm_mainloop(
    const short* __restrict__ A, const short* __restrict__ Bw,
    int m0, int n0, char* smem, f32x4 acc[4][4])
{
  const int tid = threadIdx.x;
  const int lane = tid & 63;
  const int wid = tid >> 6;
  const int wm = wid >> 1, wn = wid & 1;
  char* smA = smem;
  char* smB = smem + 8192;

  for (int k0 = 0; k0 < 512; k0 += 32) {
#pragma unroll
    for (int p = 0; p < 2; ++p) {
      int row_l = p * 64 + wid * 16 + (lane >> 2);
      int slot = (lane & 3) ^ ((row_l >> 1) & 3);
      gll16(A + ((size_t)(m0 + row_l) * 512 + k0 + slot * 8),
            smA + (p * 64 + wid * 16) * 64);
      gll16(Bw + ((size_t)(n0 + row_l) * 512 + k0 + slot * 8),
            smB + (p * 64 + wid * 16) * 64);
    }
    __syncthreads();
    bf16x8 av[4], bv[4];
#pragma unroll
    for (int mi = 0; mi < 4; ++mi) {
      int r = wm * 64 + mi * 16 + (lane & 15);
      int slot = (lane >> 4) ^ ((r >> 1) & 3);
      av[mi] = *(const bf16x8*)(smA + r * 64 + slot * 16);
    }
#pragma unroll
    for (int ni = 0; ni < 4; ++ni) {
      int r = wn * 64 + ni * 16 + (lane & 15);
      int slot = (lane >> 4) ^ ((r >> 1) & 3);
      bv[ni] = *(const bf16x8*)(smB + r * 64 + slot * 16);
    }
#pragma unroll
    for (int mi = 0; mi < 4; ++mi)
#pragma unroll
      for (int ni = 0; ni < 4; ++ni)
        acc[mi][ni] = __builtin_amdgcn_mfma_f32_16x16x32_bf16(av[mi], bv[ni], acc[mi][ni], 0, 0, 0);
    __syncthreads();
  }
}

// ---------------- QKV projection (fused Q,K,V) ----------------
__global__ __launch_bounds__(256) void k_gemm_qkv(
    const short* __restrict__ xb, const short* __restrict__ wb,
    const float* __restrict__ bq, const float* __restrict__ bk, const float* __restrict__ bv,
    short* __restrict__ Qb, short* __restrict__ Kb, short* __restrict__ Vt)
{
  __shared__ __align__(16) char smem[16384];
  const int m0 = blockIdx.x * 128;
  const int nb = blockIdx.y;
  const int sel = nb >> 2;             // 0=Q 1=K 2=V
  const int n0 = (nb & 3) * 128;
  const short* Bw = wb + (size_t)sel * 262144;
  const float* bias = sel == 0 ? bq : (sel == 1 ? bk : bv);

  f32x4 acc[4][4];
#pragma unroll
  for (int i = 0; i < 4; ++i)
#pragma unroll
    for (int j = 0; j < 4; ++j) acc[i][j] = {0.f, 0.f, 0.f, 0.f};
  gemm_mainloop(xb, Bw, m0, n0, smem, acc);

  const int lane = threadIdx.x & 63;
  const int wid = threadIdx.x >> 6;
  const int wm = wid >> 1, wn = wid & 1;
  const float scale = sel == 0 ? 0.125f : 1.0f;   // fold 1/sqrt(DK) into Q

  if (sel < 2) {
    short* O = sel == 0 ? Qb : Kb;
#pragma unroll
    for (int mi = 0; mi < 4; ++mi)
#pragma unroll
      for (int ni = 0; ni < 4; ++ni) {
        int col = n0 + wn * 64 + ni * 16 + (lane & 15);
        float bc = bias[col];
#pragma unroll
        for (int j = 0; j < 4; ++j) {
          int row = m0 + wm * 64 + mi * 16 + (lane >> 4) * 4 + j;
          O[(size_t)row * 512 + col] = (short)f2b((acc[mi][ni][j] + bc) * scale);
        }
      }
  } else {
    // V transposed: Vt[b, h, dk, t], t contiguous -> pack 4 consecutive t (8B store)
#pragma unroll
    for (int mi = 0; mi < 4; ++mi) {
      int rowb = m0 + wm * 64 + mi * 16 + (lane >> 4) * 4;
      int bidx = rowb >> 9;
      int t = rowb & 511;
#pragma unroll
      for (int ni = 0; ni < 4; ++ni) {
        int col = n0 + wn * 64 + ni * 16 + (lane & 15);
        float bc = bias[col];
        u16x4 pk;
#pragma unroll
        for (int j = 0; j < 4; ++j) pk[j] = f2b(acc[mi][ni][j] + bc);
        *(u16x4*)&Vt[(((size_t)bidx * 8 + (col >> 6)) * 64 + (col & 63)) * 512 + t] = pk;
      }
    }
  }
}

// ---------------- output projection ----------------
__global__ __launch_bounds__(256) void k_gemm_out(
    const short* __restrict__ AO, const short* __restrict__ Wob,
    const float* __restrict__ bo, float* __restrict__ out)
{
  __shared__ __align__(16) char smem[16384];
  const int m0 = blockIdx.x * 128;
  const int n0 = blockIdx.y * 128;
  f32x4 acc[4][4];
#pragma unroll
  for (int i = 0; i < 4; ++i)
#pragma unroll
    for (int j = 0; j < 4; ++j) acc[i][j] = {0.f, 0.f, 0.f, 0.f};
  gemm_mainloop(AO, Wob, m0, n0, smem, acc);

  const int lane = threadIdx.x & 63;
  const int wid = threadIdx.x >> 6;
  const int wm = wid >> 1, wn = wid & 1;
#pragma unroll
  for (int mi = 0; mi < 4; ++mi)
#pragma unroll
    for (int ni = 0; ni < 4; ++ni) {
      int col = n0 + wn * 64 + ni * 16 + (lane & 15);
      float bc = bo[col];
#pragma unroll
      for (int j = 0; j < 4; ++j) {
        int row = m0 + wm * 64 + mi * 16 + (lane >> 4) * 4 + j;
        out[(size_t)row * 512 + col] = acc[mi][ni][j] + bc;
      }
    }
}

// ---------------- flash attention with rel-pos bias + key padding mask ------
// Block: 4 waves, 64 q-rows (wave w owns rows w*16..+15). KBLK=64 (8 tiles).
// Q pre-scaled by 1/8. bias[h,q,k] = rel[(k-q+511)*8+h] (clip is a no-op at
// T==MAX_LEN). Mask: s_km[k] = -inf for padded keys.
__global__ __launch_bounds__(256) void k_attn(
    const short* __restrict__ Qb, const short* __restrict__ Kb, const short* __restrict__ Vt,
    const float* __restrict__ rel, const int* __restrict__ kpm,
    short* __restrict__ AO)
{
  const int qt = blockIdx.x;
  const int bh = blockIdx.y;
  const int b = bh >> 3, h = bh & 7;
  const int tid = threadIdx.x;
  const int lane = tid & 63;
  const int w = tid >> 6;
  const int g = lane >> 4;
  const int x15 = lane & 15;

  __shared__ float s_rel[1024];
  __shared__ float s_km[512];
  __shared__ __align__(16) short s_p[4][16][72];   // pitch 72: 2-way-free b128 reads

  for (int i = tid; i < 1023; i += 256) s_rel[i] = rel[i * 8 + h];
  for (int t = tid; t < 512; t += 256) s_km[t] = kpm[b * 512 + t] ? -INFINITY : 0.0f;
  __syncthreads();

  const int qr = qt * 64 + w * 16 + x15;
  const short* qp = Qb + ((size_t)(b * 512 + qr)) * 512 + h * 64 + g * 8;
  bf16x8 qf[2];
  qf[0] = *(const bf16x8*)qp;
  qf[1] = *(const bf16x8*)(qp + 32);

  float mrow[4], lrow[4];
  f32x4 acc_o[4];
#pragma unroll
  for (int j = 0; j < 4; ++j) { mrow[j] = -INFINITY; lrow[j] = 0.f; }
#pragma unroll
  for (int ni = 0; ni < 4; ++ni) acc_o[ni] = {0.f, 0.f, 0.f, 0.f};

  const int q0 = qt * 64 + w * 16 + g * 4;   // + j = this lane's 4 q rows

  for (int kt = 0; kt < 8; ++kt) {
    const int k0 = kt * 64;
    f32x4 s[4];
#pragma unroll
    for (int ni = 0; ni < 4; ++ni) s[ni] = {0.f, 0.f, 0.f, 0.f};
    // S = Q K^T  (B-frag = contiguous row reads of K, L2-resident)
#pragma unroll
    for (int ks = 0; ks < 2; ++ks)
#pragma unroll
      for (int ni = 0; ni < 4; ++ni) {
        const short* kp = Kb + ((size_t)(b * 512 + k0 + ni * 16 + x15)) * 512 + h * 64 + ks * 32 + g * 8;
        bf16x8 kf = *(const bf16x8*)kp;
        s[ni] = __builtin_amdgcn_mfma_f32_16x16x32_bf16(qf[ks], kf, s[ni], 0, 0, 0);
      }
    // bias + mask, row max
    float sv[4][4];
    float rmax[4] = {-INFINITY, -INFINITY, -INFINITY, -INFINITY};
#pragma unroll
    for (int ni = 0; ni < 4; ++ni) {
      int k = k0 + ni * 16 + x15;
      float km = s_km[k];
#pragma unroll
      for (int j = 0; j < 4; ++j) {
        float v = s[ni][j] + s_rel[k - (q0 + j) + 511] + km;
        sv[ni][j] = v;
        rmax[j] = fmaxf(rmax[j], v);
      }
    }
#pragma unroll
    for (int off = 1; off < 16; off <<= 1)
#pragma unroll
      for (int j = 0; j < 4; ++j)
        rmax[j] = fmaxf(rmax[j], __shfl_xor(rmax[j], off, 64));
    float mn[4], sc[4], ps[4];
#pragma unroll
    for (int j = 0; j < 4; ++j) {
      mn[j] = fmaxf(mrow[j], rmax[j]);
      sc[j] = __expf(mrow[j] - mn[j]);   // exp(-inf)=0 on first tile
      ps[j] = 0.f;
    }
#pragma unroll
    for (int ni = 0; ni < 4; ++ni)
#pragma unroll
      for (int j = 0; j < 4; ++j) {
        float pe = __expf(sv[ni][j] - mn[j]);
        sv[ni][j] = pe;
        ps[j] += pe;
      }
#pragma unroll
    for (int off = 1; off < 16; off <<= 1)
#pragma unroll
      for (int j = 0; j < 4; ++j)
        ps[j] += __shfl_xor(ps[j], off, 64);
#pragma unroll
    for (int j = 0; j < 4; ++j) {
      lrow[j] = lrow[j] * sc[j] + ps[j];
      mrow[j] = mn[j];
    }
#pragma unroll
    for (int ni = 0; ni < 4; ++ni)
#pragma unroll
      for (int j = 0; j < 4; ++j)
        acc_o[ni][j] *= sc[j];
    // P (C-layout) -> LDS -> A-frag layout; per-wave region, no barrier needed
#pragma unroll
    for (int ni = 0; ni < 4; ++ni)
#pragma unroll
      for (int j = 0; j < 4; ++j)
        s_p[w][g * 4 + j][x15 + ni * 16] = (short)f2b(sv[ni][j]);
#pragma unroll
    for (int ks = 0; ks < 2; ++ks) {
      bf16x8 pf = *(const bf16x8*)&s_p[w][x15][ks * 32 + g * 8];
#pragma unroll
      for (int ni = 0; ni < 4; ++ni) {
        const short* vp = Vt + (((size_t)(b * 8 + h)) * 64 + ni * 16 + x15) * 512 + k0 + ks * 32 + g * 8;
        bf16x8 vf = *(const bf16x8*)vp;
        acc_o[ni] = __builtin_amdgcn_mfma_f32_16x16x32_bf16(pf, vf, acc_o[ni], 0, 0, 0);
      }
    }
  }
#pragma unroll
  for (int j = 0; j < 4; ++j) lrow[j] = 1.f / lrow[j];
#pragma unroll
  for (int ni = 0; ni < 4; ++ni)
#pragma unroll
    for (int j = 0; j < 4; ++j) {
      int row = b * 512 + q0 + j;
      AO[(size_t)row * 512 + h * 64 + ni * 16 + x15] = (short)f2b(acc_o[ni][j] * lrow[j]);
    }
}

extern "C" void kernel_launch(void* const* d_in, const int* in_sizes, int n_in,
                              void* d_out, int out_size, void* d_ws, size_t ws_size,
                              hipStream_t stream) {
  const float* x   = (const float*)d_in[0];
  const float* Wq  = (const float*)d_in[1];
  const float* bq  = (const float*)d_in[2];
  const float* Wk  = (const float*)d_in[3];
  const float* bk  = (const float*)d_in[4];
  const float* Wv  = (const float*)d_in[5];
  const float* bv  = (const float*)d_in[6];
  const float* Wo  = (const float*)d_in[7];
  const float* bo  = (const float*)d_in[8];
  const float* rel = (const float*)d_in[9];
  const int*   kpm = (const int*)d_in[10];   // bool mask, assumed int32 storage
  float* out = (float*)d_out;

  // ws layout (bf16 elements): xb[8M] wb[1M] Qb[8M] Kb[8M] Vt[8M] AO[8M] = 86MB
  short* xb = (short*)d_ws;
  short* wb = xb + (size_t)8388608;
  short* Qb = wb + (size_t)1048576;
  short* Kb = Qb + (size_t)8388608;
  short* Vt = Kb + (size_t)8388608;
  short* AO = Vt + (size_t)8388608;

  k_cvt<<<9216, 256, 0, stream>>>(x, Wq, Wk, Wv, Wo, xb, wb);
  k_gemm_qkv<<<dim3(128, 12), 256, 0, stream>>>(xb, wb, bq, bk, bv, Qb, Kb, Vt);
  k_attn<<<dim3(8, 256), 256, 0, stream>>>(Qb, Kb, Vt, rel, kpm, AO);
  k_gemm_out<<<dim3(128, 4), 256, 0, stream>>>(AO, wb + (size_t)3 * 262144, bo, out);
}

// Round 3
// 195.224 us; speedup vs baseline: 1.4388x; 1.4388x over previous
//
#include <hip/hip_runtime.h>
#include <cstdint>
#include <cstddef>
#include <cmath>

// RelPosMHA: x[32,512,512] f32 -> QKV proj -> rel-pos-bias attention -> out proj.
//  - k_cvt: f32 -> bf16 for x and Wq/Wk/Wv/Wo.
//  - k_gemm_qkv: 128x128 bf16 MFMA GEMM (BK=32, global_load_lds w=16, XOR slot
//    swizzle). Q scaled 1/8; V written transposed [b,h,dk,t].
//  - k_attn v3: one block per (b,h); K,V slices fully staged in LDS (128 KB,
//    slot-swizzled via pre-swizzled GLOBAL source + wave-uniform LDS base --
//    the documented global_load_lds contract; v2's per-lane LDS dest was the
//    NaN bug). Swapped QK^T (key axis lane-local) -> softmax reduce is
//    2 shfl_xor; defer-max (THR=8); P packed via v_cvt_pk into b64 writes.
//    All sentinels finite (-1e30), no inf arithmetic anywhere.
//  - k_gemm_out: GEMM, f32 epilogue + bias -> d_out.

typedef __attribute__((ext_vector_type(8))) short bf16x8;
typedef __attribute__((ext_vector_type(4))) float f32x4;
typedef __attribute__((ext_vector_type(4))) unsigned short u16x4;
typedef __attribute__((ext_vector_type(2))) unsigned int u32x2;

typedef __attribute__((address_space(3))) unsigned int lds_u32;
typedef const __attribute__((address_space(1))) unsigned int glb_u32;

#define NEG_BIG (-1.0e30f)

__device__ __forceinline__ unsigned short f2b(float f) {
  unsigned int u = __builtin_bit_cast(unsigned int, f);
  u += 0x7fffu + ((u >> 16) & 1u);   // RNE (no NaN inputs in this pipeline)
  return (unsigned short)(u >> 16);
}

__device__ __forceinline__ unsigned int cvtpk(float lo, float hi) {
  unsigned int r;
  asm("v_cvt_pk_bf16_f32 %0, %1, %2" : "=v"(r) : "v"(lo), "v"(hi));
  return r;
}

__device__ __forceinline__ void gll16(const void* g, void* l) {
  __builtin_amdgcn_global_load_lds((glb_u32*)g, (lds_u32*)l, 16, 0, 0);
}

// ---------------- convert f32 -> bf16 (x + 4 weights) ----------------
__global__ __launch_bounds__(256) void k_cvt(
    const float* __restrict__ x,
    const float* __restrict__ w0, const float* __restrict__ w1,
    const float* __restrict__ w2, const float* __restrict__ w3,
    short* __restrict__ xb, short* __restrict__ wb)
{
  size_t i = (size_t)blockIdx.x * 256 + threadIdx.x;
  size_t e = i * 4;
  const float* s;
  short* d;
  if (e < (size_t)8388608) { s = x + e; d = xb + e; }
  else {
    size_t r = e - 8388608;
    int ws = (int)(r >> 18);
    const float* wp = ws == 0 ? w0 : ws == 1 ? w1 : ws == 2 ? w2 : w3;
    s = wp + (r & 262143);
    d = wb + r;
  }
  f32x4 v = *(const f32x4*)s;
  u16x4 o;
  o.x = f2b(v.x); o.y = f2b(v.y); o.z = f2b(v.z); o.w = f2b(v.w);
  *(u16x4*)d = o;
}

// ---------------- shared GEMM mainloop: C[128x128] += A[128xK] * B[128xK]^T ----
__device__ __forceinline__ void gemm_mainloop(
    const short* __restrict__ A, const short* __restrict__ Bw,
    int m0, int n0, char* smem, f32x4 acc[4][4])
{
  const int tid = threadIdx.x;
  const int lane = tid & 63;
  const int wid = tid >> 6;
  const int wm = wid >> 1, wn = wid & 1;
  char* smA = smem;
  char* smB = smem + 8192;

  for (int k0 = 0; k0 < 512; k0 += 32) {
#pragma unroll
    for (int p = 0; p < 2; ++p) {
      int row_l = p * 64 + wid * 16 + (lane >> 2);
      int slot = (lane & 3) ^ ((row_l >> 1) & 3);
      gll16(A + ((size_t)(m0 + row_l) * 512 + k0 + slot * 8),
            smA + (p * 64 + wid * 16) * 64);
      gll16(Bw + ((size_t)(n0 + row_l) * 512 + k0 + slot * 8),
            smB + (p * 64 + wid * 16) * 64);
    }
    __syncthreads();
    bf16x8 av[4], bv[4];
#pragma unroll
    for (int mi = 0; mi < 4; ++mi) {
      int r = wm * 64 + mi * 16 + (lane & 15);
      int slot = (lane >> 4) ^ ((r >> 1) & 3);
      av[mi] = *(const bf16x8*)(smA + r * 64 + slot * 16);
    }
#pragma unroll
    for (int ni = 0; ni < 4; ++ni) {
      int r = wn * 64 + ni * 16 + (lane & 15);
      int slot = (lane >> 4) ^ ((r >> 1) & 3);
      bv[ni] = *(const bf16x8*)(smB + r * 64 + slot * 16);
    }
#pragma unroll
    for (int mi = 0; mi < 4; ++mi)
#pragma unroll
      for (int ni = 0; ni < 4; ++ni)
        acc[mi][ni] = __builtin_amdgcn_mfma_f32_16x16x32_bf16(av[mi], bv[ni], acc[mi][ni], 0, 0, 0);
    __syncthreads();
  }
}

// ---------------- QKV projection (fused Q,K,V) ----------------
__global__ __launch_bounds__(256) void k_gemm_qkv(
    const short* __restrict__ xb, const short* __restrict__ wb,
    const float* __restrict__ bq, const float* __restrict__ bk, const float* __restrict__ bv,
    short* __restrict__ Qb, short* __restrict__ Kb, short* __restrict__ Vt)
{
  __shared__ __align__(16) char smem[16384];
  const int m0 = blockIdx.x * 128;
  const int nb = blockIdx.y;
  const int sel = nb >> 2;             // 0=Q 1=K 2=V
  const int n0 = (nb & 3) * 128;
  const short* Bw = wb + (size_t)sel * 262144;
  const float* bias = sel == 0 ? bq : (sel == 1 ? bk : bv);

  f32x4 acc[4][4];
#pragma unroll
  for (int i = 0; i < 4; ++i)
#pragma unroll
    for (int j = 0; j < 4; ++j) acc[i][j] = {0.f, 0.f, 0.f, 0.f};
  gemm_mainloop(xb, Bw, m0, n0, smem, acc);

  const int lane = threadIdx.x & 63;
  const int wid = threadIdx.x >> 6;
  const int wm = wid >> 1, wn = wid & 1;
  const float scale = sel == 0 ? 0.125f : 1.0f;   // fold 1/sqrt(DK) into Q

  if (sel < 2) {
    short* O = sel == 0 ? Qb : Kb;
#pragma unroll
    for (int mi = 0; mi < 4; ++mi)
#pragma unroll
      for (int ni = 0; ni < 4; ++ni) {
        int col = n0 + wn * 64 + ni * 16 + (lane & 15);
        float bc = bias[col];
#pragma unroll
        for (int j = 0; j < 4; ++j) {
          int row = m0 + wm * 64 + mi * 16 + (lane >> 4) * 4 + j;
          O[(size_t)row * 512 + col] = (short)f2b((acc[mi][ni][j] + bc) * scale);
        }
      }
  } else {
#pragma unroll
    for (int mi = 0; mi < 4; ++mi) {
      int rowb = m0 + wm * 64 + mi * 16 + (lane >> 4) * 4;
      int bidx = rowb >> 9;
      int t = rowb & 511;
#pragma unroll
      for (int ni = 0; ni < 4; ++ni) {
        int col = n0 + wn * 64 + ni * 16 + (lane & 15);
        float bc = bias[col];
        u16x4 pk;
#pragma unroll
        for (int j = 0; j < 4; ++j) pk[j] = f2b(acc[mi][ni][j] + bc);
        *(u16x4*)&Vt[(((size_t)bidx * 8 + (col >> 6)) * 64 + (col & 63)) * 512 + t] = pk;
      }
    }
  }
}

// ---------------- output projection ----------------
__global__ __launch_bounds__(256) void k_gemm_out(
    const short* __restrict__ AO, const short* __restrict__ Wob,
    const float* __restrict__ bo, float* __restrict__ out)
{
  __shared__ __align__(16) char smem[16384];
  const int m0 = blockIdx.x * 128;
  const int n0 = blockIdx.y * 128;
  f32x4 acc[4][4];
#pragma unroll
  for (int i = 0; i < 4; ++i)
#pragma unroll
    for (int j = 0; j < 4; ++j) acc[i][j] = {0.f, 0.f, 0.f, 0.f};
  gemm_mainloop(AO, Wob, m0, n0, smem, acc);

  const int lane = threadIdx.x & 63;
  const int wid = threadIdx.x >> 6;
  const int wm = wid >> 1, wn = wid & 1;
#pragma unroll
  for (int mi = 0; mi < 4; ++mi)
#pragma unroll
    for (int ni = 0; ni < 4; ++ni) {
      int col = n0 + wn * 64 + ni * 16 + (lane & 15);
      float bc = bo[col];
#pragma unroll
      for (int j = 0; j < 4; ++j) {
        int row = m0 + wm * 64 + mi * 16 + (lane >> 4) * 4 + j;
        out[(size_t)row * 512 + col] = acc[mi][ni][j] + bc;
      }
    }
}

// ---------------- flash attention v3: block per (b,h), K/V in LDS ----------
// 8 waves x 64 q-rows. Swapped QK^T: S = mfma(K-frag, Q-frag) -> lane (g,x15)
// holds S[key=k0+16ki+4g+j][q=x15 within mi-tile]. Row reductions are in-lane
// + 2 shfl_xor(16,32). PV: P repacked (cvt_pk pairs) into per-wave swizzled
// LDS tile, read back as A-frag; V B-frags from LDS. O lands transposed
// (q=g*4+jj, dk=x15) -> per-row 1/l fetched by shfl at the end.
__global__ __launch_bounds__(512, 2) void k_attn(
    const short* __restrict__ Qb, const short* __restrict__ Kb, const short* __restrict__ Vt,
    const float* __restrict__ rel, const int* __restrict__ kpm,
    short* __restrict__ AO)
{
  const int bh = blockIdx.x;
  const int b = bh >> 3, h = bh & 7;
  const int tid = threadIdx.x;
  const int lane = tid & 63;
  const int w = tid >> 6;
  const int g = lane >> 4;
  const int x15 = lane & 15;

  __shared__ __align__(16) short s_k[32768];   // [512 rows][64] 16B-slot swizzled
  __shared__ __align__(16) short s_v[32768];   // [64 rows][512] slot swizzled
  __shared__ float s_rel[1024];
  __shared__ float s_km[512];
  __shared__ __align__(16) short s_p[8][1024]; // per-wave [16 q][64 k] swizzled

  // ---- stage K and V (64 KB each). LDS dest is WAVE-UNIFORM base (hardware
  // adds lane*16); the slot swizzle rides on the per-lane GLOBAL address.
#pragma unroll
  for (int it = 0; it < 8; ++it) {
    const int ub = it * 512 + w * 64;            // wave-uniform 16B-unit base
    const int u = ub + lane;                     // this lane's unit
    const int rk = u >> 3, sk = (u & 7) ^ (rk & 7);
    gll16(Kb + ((size_t)(b * 512 + rk)) * 512 + h * 64 + sk * 8,
          (char*)s_k + (size_t)ub * 16);
    const int rv = u >> 6, sv2 = (u & 63) ^ (rv & 7);
    gll16(Vt + ((size_t)((b * 8 + h) * 64 + rv)) * 512 + sv2 * 8,
          (char*)s_v + (size_t)ub * 16);
  }
  for (int i = tid; i < 1023; i += 512) s_rel[i] = rel[i * 8 + h];
  s_km[tid] = kpm[b * 512 + tid] ? NEG_BIG : 0.0f;

  // ---- Q fragments: wave w owns q rows w*64 .. +63 (4 tiles of 16)
  bf16x8 qf[4][2];
#pragma unroll
  for (int mi = 0; mi < 4; ++mi)
#pragma unroll
    for (int ks = 0; ks < 2; ++ks)
      qf[mi][ks] = *(const bf16x8*)(Qb + ((size_t)(b * 512 + w * 64 + mi * 16 + x15)) * 512
                                    + h * 64 + ks * 32 + g * 8);
  __syncthreads();

  float m_r[4], l_r[4];
  f32x4 acc[4][4];
#pragma unroll
  for (int mi = 0; mi < 4; ++mi) { m_r[mi] = NEG_BIG; l_r[mi] = 0.f; }
#pragma unroll
  for (int mi = 0; mi < 4; ++mi)
#pragma unroll
    for (int ni = 0; ni < 4; ++ni) acc[mi][ni] = {0.f, 0.f, 0.f, 0.f};

  for (int kt = 0; kt < 8; ++kt) {
    const int k0 = kt * 64;
    // K fragments from LDS
    bf16x8 kf[4][2];
#pragma unroll
    for (int ki = 0; ki < 4; ++ki)
#pragma unroll
      for (int ks = 0; ks < 2; ++ks) {
        int r = k0 + ki * 16 + x15;
        int p = (ks * 4 + g) ^ (x15 & 7);
        kf[ki][ks] = *(const bf16x8*)((const char*)s_k + r * 128 + p * 16);
      }
    // V fragments (mi-invariant)
    bf16x8 vf[2][4];
#pragma unroll
    for (int ks = 0; ks < 2; ++ks)
#pragma unroll
      for (int ni = 0; ni < 4; ++ni) {
        int r = ni * 16 + x15;
        int p = kt * 8 + ((ks * 4 + g) ^ (x15 & 7));
        vf[ks][ni] = *(const bf16x8*)((const char*)s_v + r * 1024 + p * 16);
      }
    // key mask values (mi-invariant; x15-invariant broadcast reads)
    float kmv[4][4];
#pragma unroll
    for (int ki = 0; ki < 4; ++ki)
#pragma unroll
      for (int j = 0; j < 4; ++j)
        kmv[ki][j] = s_km[k0 + ki * 16 + g * 4 + j];

    short* pw = s_p[w];
#pragma unroll
    for (int mi = 0; mi < 4; ++mi) {
      // S = K Q^T (keys on C-rows, q on C-cols): 8 MFMA
      f32x4 s[4];
#pragma unroll
      for (int ki = 0; ki < 4; ++ki) s[ki] = {0.f, 0.f, 0.f, 0.f};
#pragma unroll
      for (int ks = 0; ks < 2; ++ks)
#pragma unroll
        for (int ki = 0; ki < 4; ++ki)
          s[ki] = __builtin_amdgcn_mfma_f32_16x16x32_bf16(kf[ki][ks], qf[mi][ks], s[ki], 0, 0, 0);

      const int rbase = k0 + 511 - (w * 64 + mi * 16 + x15) + g * 4;
      float sv[4][4];
      float pmax = NEG_BIG;
#pragma unroll
      for (int ki = 0; ki < 4; ++ki)
#pragma unroll
        for (int j = 0; j < 4; ++j) {
          float v2 = s[ki][j] + s_rel[rbase + ki * 16 + j] + kmv[ki][j];
          sv[ki][j] = v2;
          pmax = fmaxf(pmax, v2);
        }
      // defer-max: skip reduce+rescale unless some lane exceeds m+8
      if (!__all(pmax - m_r[mi] <= 8.0f)) {
        float rm = fmaxf(pmax, __shfl_xor(pmax, 16, 64));
        rm = fmaxf(rm, __shfl_xor(rm, 32, 64));
        float mn = fmaxf(m_r[mi], rm);
        float sc = __expf(m_r[mi] - mn);
        l_r[mi] *= sc;
        m_r[mi] = mn;
        // rescale acc (O-layout rows q=g*4+jj need sc from lane x15=q; sc is
        // g-invariant so stay within the same 16-lane group)
        float scO[4];
#pragma unroll
        for (int jj = 0; jj < 4; ++jj)
          scO[jj] = __shfl(sc, (lane & 48) | (g * 4 + jj), 64);
#pragma unroll
        for (int ni = 0; ni < 4; ++ni)
#pragma unroll
          for (int jj = 0; jj < 4; ++jj) acc[mi][ni][jj] *= scO[jj];
      }
      float ps = 0.f;
      unsigned int pk[4][2];
#pragma unroll
      for (int ki = 0; ki < 4; ++ki) {
#pragma unroll
        for (int j = 0; j < 4; ++j) {
          float pe = __expf(sv[ki][j] - m_r[mi]);
          sv[ki][j] = pe;
          ps += pe;
        }
        pk[ki][0] = cvtpk(sv[ki][0], sv[ki][1]);
        pk[ki][1] = cvtpk(sv[ki][2], sv[ki][3]);
      }
      ps += __shfl_xor(ps, 16, 64);
      ps += __shfl_xor(ps, 32, 64);
      l_r[mi] += ps;
      // P -> per-wave swizzled LDS tile ([q=x15 row][key], 8B per ki)
#pragma unroll
      for (int ki = 0; ki < 4; ++ki) {
        int p = (2 * ki + (g >> 1)) ^ (x15 & 7);
        u32x2 pr; pr.x = pk[ki][0]; pr.y = pk[ki][1];
        *(u32x2*)((char*)pw + x15 * 128 + p * 16 + (g & 1) * 8) = pr;
      }
      // read back as A-frag, PV: 8 MFMA
      bf16x8 pf[2];
#pragma unroll
      for (int ks = 0; ks < 2; ++ks) {
        int p = (ks * 4 + g) ^ (x15 & 7);
        pf[ks] = *(const bf16x8*)((const char*)pw + x15 * 128 + p * 16);
      }
#pragma unroll
      for (int ks = 0; ks < 2; ++ks)
#pragma unroll
        for (int ni = 0; ni < 4; ++ni)
          acc[mi][ni] = __builtin_amdgcn_mfma_f32_16x16x32_bf16(pf[ks], vf[ks][ni], acc[mi][ni], 0, 0, 0);
    }
  }

  // ---- epilogue: O[q=g*4+jj][dk=x15+16ni], 1/l fetched from lane x15=q
#pragma unroll
  for (int mi = 0; mi < 4; ++mi) {
    float li = 1.0f / l_r[mi];
    float liO[4];
#pragma unroll
    for (int jj = 0; jj < 4; ++jj)
      liO[jj] = __shfl(li, (lane & 48) | (g * 4 + jj), 64);
#pragma unroll
    for (int ni = 0; ni < 4; ++ni)
#pragma unroll
      for (int jj = 0; jj < 4; ++jj) {
        int q = w * 64 + mi * 16 + g * 4 + jj;
        AO[((size_t)(b * 512 + q)) * 512 + h * 64 + ni * 16 + x15] =
            (short)f2b(acc[mi][ni][jj] * liO[jj]);
      }
  }
}

extern "C" void kernel_launch(void* const* d_in, const int* in_sizes, int n_in,
                              void* d_out, int out_size, void* d_ws, size_t ws_size,
                              hipStream_t stream) {
  const float* x   = (const float*)d_in[0];
  const float* Wq  = (const float*)d_in[1];
  const float* bq  = (const float*)d_in[2];
  const float* Wk  = (const float*)d_in[3];
  const float* bk  = (const float*)d_in[4];
  const float* Wv  = (const float*)d_in[5];
  const float* bv  = (const float*)d_in[6];
  const float* Wo  = (const float*)d_in[7];
  const float* bo  = (const float*)d_in[8];
  const float* rel = (const float*)d_in[9];
  const int*   kpm = (const int*)d_in[10];
  float* out = (float*)d_out;

  // ws layout (bf16 elements): xb[8M] wb[1M] Qb[8M] Kb[8M] Vt[8M] AO[8M]
  short* xb = (short*)d_ws;
  short* wb = xb + (size_t)8388608;
  short* Qb = wb + (size_t)1048576;
  short* Kb = Qb + (size_t)8388608;
  short* Vt = Kb + (size_t)8388608;
  short* AO = Vt + (size_t)8388608;

  k_cvt<<<9216, 256, 0, stream>>>(x, Wq, Wk, Wv, Wo, xb, wb);
  k_gemm_qkv<<<dim3(128, 12), 256, 0, stream>>>(xb, wb, bq, bk, bv, Qb, Kb, Vt);
  k_attn<<<256, 512, 0, stream>>>(Qb, Kb, Vt, rel, kpm, AO);
  k_gemm_out<<<dim3(128, 4), 256, 0, stream>>>(AO, wb + (size_t)3 * 262144, bo, out);
}

// Round 8
// 191.548 us; speedup vs baseline: 1.4664x; 1.0192x over previous
//
#include <hip/hip_runtime.h>
#include <cstdint>
#include <cstddef>
#include <cmath>

// RelPosMHA: x[32,512,512] f32 -> QKV proj -> rel-pos-bias attention -> out proj.
//  - k_cvt: f32 -> bf16 for x and Wq/Wk/Wv/Wo.
//  - k_gemm_qkv / k_gemm_out: 128x128 bf16 MFMA GEMM, BK=64 single-buffered
//    (round-3-verified sync template: STAGE; barrier; COMPUTE; barrier --
//    BK=64 is a parameter change of that template; cold-verified round 7).
//    global_load_lds w=16, 8-slot XOR swizzle (slot ^ (row&7)).
//  - k_attn v3 (BYTE-IDENTICAL to the fully-green round-3 kernel): one block
//    per (b,h); K,V slices staged in LDS via wave-uniform global_load_lds;
//    swapped QK^T; defer-max; cvt_pk P-pack via short-typed per-wave tile.
//    The v4-v6 attn rewrites (direct K/V global loads) carried a warm-timing
//    race (round 7: cold launch correct, all warm launches wrong) and are
//    abandoned.

typedef __attribute__((ext_vector_type(8))) short bf16x8;
typedef __attribute__((ext_vector_type(4))) float f32x4;
typedef __attribute__((ext_vector_type(4))) unsigned short u16x4;
typedef __attribute__((ext_vector_type(2))) unsigned int u32x2;

typedef __attribute__((address_space(3))) unsigned int lds_u32;
typedef const __attribute__((address_space(1))) unsigned int glb_u32;

#define NEG_BIG (-1.0e30f)

__device__ __forceinline__ unsigned short f2b(float f) {
  unsigned int u = __builtin_bit_cast(unsigned int, f);
  u += 0x7fffu + ((u >> 16) & 1u);   // RNE (no NaN inputs in this pipeline)
  return (unsigned short)(u >> 16);
}

__device__ __forceinline__ unsigned int cvtpk(float lo, float hi) {
  unsigned int r;
  asm("v_cvt_pk_bf16_f32 %0, %1, %2" : "=v"(r) : "v"(lo), "v"(hi));
  return r;
}

__device__ __forceinline__ void gll16(const void* g, void* l) {
  __builtin_amdgcn_global_load_lds((glb_u32*)g, (lds_u32*)l, 16, 0, 0);
}

// ---------------- convert f32 -> bf16 (x + 4 weights) ----------------
__global__ __launch_bounds__(256) void k_cvt(
    const float* __restrict__ x,
    const float* __restrict__ w0, const float* __restrict__ w1,
    const float* __restrict__ w2, const float* __restrict__ w3,
    short* __restrict__ xb, short* __restrict__ wb)
{
  size_t i = (size_t)blockIdx.x * 256 + threadIdx.x;
  size_t e = i * 4;
  const float* s;
  short* d;
  if (e < (size_t)8388608) { s = x + e; d = xb + e; }
  else {
    size_t r = e - 8388608;
    int ws = (int)(r >> 18);
    const float* wp = ws == 0 ? w0 : ws == 1 ? w1 : ws == 2 ? w2 : w3;
    s = wp + (r & 262143);
    d = wb + r;
  }
  f32x4 v = *(const f32x4*)s;
  u16x4 o;
  o.x = f2b(v.x); o.y = f2b(v.y); o.z = f2b(v.z); o.w = f2b(v.w);
  *(u16x4*)d = o;
}

// ------- GEMM mainloop: C[128x128] += A[128x512] * B[128x512]^T, BK=64 ------
// smem: A tile [128 rows][64 bf16] at 0 (16 KB), B tile at +16384. 8 16B slots
// per row; LDS slot l of row r holds global slot l ^ (r&7). Staged via
// global_load_lds w=16 with wave-uniform LDS base (lane x16 appended by HW),
// swizzle applied on the per-lane GLOBAL address.
__device__ __forceinline__ void gemm_mainloop(
    const short* __restrict__ A, const short* __restrict__ Bw,
    int m0, int n0, char* smem, f32x4 acc[4][4])
{
  const int tid = threadIdx.x;
  const int lane = tid & 63;
  const int wid = tid >> 6;
  const int wm = wid >> 1, wn = wid & 1;
  const int g = lane >> 4;
  const int x15 = lane & 15;
  char* smA = smem;
  char* smB = smem + 16384;

#pragma unroll 1
  for (int kk = 0; kk < 512; kk += 64) {
#pragma unroll
    for (int p = 0; p < 4; ++p) {
      int ub = p * 256 + wid * 64;          // wave-uniform 16B-unit base
      int u = ub + lane;
      int row = u >> 3;
      int gs = (u & 7) ^ (row & 7);
      gll16(A + ((size_t)(m0 + row) * 512 + kk + gs * 8), smA + ub * 16);
      gll16(Bw + ((size_t)(n0 + row) * 512 + kk + gs * 8), smB + ub * 16);
    }
    __syncthreads();                        // compiler drains vmcnt before barrier
    bf16x8 av[4][2], bv[4][2];
#pragma unroll
    for (int mi = 0; mi < 4; ++mi)
#pragma unroll
      for (int ks = 0; ks < 2; ++ks) {
        int r = wm * 64 + mi * 16 + x15;
        int sl = (ks * 4 + g) ^ (x15 & 7);
        av[mi][ks] = *(const bf16x8*)(smA + r * 128 + sl * 16);
      }
#pragma unroll
    for (int ni = 0; ni < 4; ++ni)
#pragma unroll
      for (int ks = 0; ks < 2; ++ks) {
        int r = wn * 64 + ni * 16 + x15;
        int sl = (ks * 4 + g) ^ (x15 & 7);
        bv[ni][ks] = *(const bf16x8*)(smB + r * 128 + sl * 16);
      }
#pragma unroll
    for (int ks = 0; ks < 2; ++ks)
#pragma unroll
      for (int mi = 0; mi < 4; ++mi)
#pragma unroll
        for (int ni = 0; ni < 4; ++ni)
          acc[mi][ni] = __builtin_amdgcn_mfma_f32_16x16x32_bf16(av[mi][ks], bv[ni][ks], acc[mi][ni], 0, 0, 0);
    __syncthreads();                        // reads done before next stage
  }
}

// ---------------- QKV projection (fused Q,K,V) ----------------
__global__ __launch_bounds__(256) void k_gemm_qkv(
    const short* __restrict__ xb, const short* __restrict__ wb,
    const float* __restrict__ bq, const float* __restrict__ bk, const float* __restrict__ bv,
    short* __restrict__ Qb, short* __restrict__ Kb, short* __restrict__ Vt)
{
  __shared__ __align__(16) char smem[32768];
  const int m0 = blockIdx.x * 128;
  const int nb = blockIdx.y;
  const int sel = nb >> 2;             // 0=Q 1=K 2=V
  const int n0 = (nb & 3) * 128;
  const short* Bw = wb + (size_t)sel * 262144;
  const float* bias = sel == 0 ? bq : (sel == 1 ? bk : bv);

  f32x4 acc[4][4];
#pragma unroll
  for (int i = 0; i < 4; ++i)
#pragma unroll
    for (int j = 0; j < 4; ++j) acc[i][j] = {0.f, 0.f, 0.f, 0.f};
  gemm_mainloop(xb, Bw, m0, n0, smem, acc);

  const int lane = threadIdx.x & 63;
  const int wid = threadIdx.x >> 6;
  const int wm = wid >> 1, wn = wid & 1;
  const float scale = sel == 0 ? 0.125f : 1.0f;   // fold 1/sqrt(DK) into Q

  if (sel < 2) {
    short* O = sel == 0 ? Qb : Kb;
#pragma unroll
    for (int mi = 0; mi < 4; ++mi)
#pragma unroll
      for (int ni = 0; ni < 4; ++ni) {
        int col = n0 + wn * 64 + ni * 16 + (lane & 15);
        float bc = bias[col];
#pragma unroll
        for (int j = 0; j < 4; ++j) {
          int row = m0 + wm * 64 + mi * 16 + (lane >> 4) * 4 + j;
          O[(size_t)row * 512 + col] = (short)f2b((acc[mi][ni][j] + bc) * scale);
        }
      }
  } else {
#pragma unroll
    for (int mi = 0; mi < 4; ++mi) {
      int rowb = m0 + wm * 64 + mi * 16 + (lane >> 4) * 4;
      int bidx = rowb >> 9;
      int t = rowb & 511;
#pragma unroll
      for (int ni = 0; ni < 4; ++ni) {
        int col = n0 + wn * 64 + ni * 16 + (lane & 15);
        float bc = bias[col];
        u16x4 pk;
#pragma unroll
        for (int j = 0; j < 4; ++j) pk[j] = f2b(acc[mi][ni][j] + bc);
        *(u16x4*)&Vt[(((size_t)bidx * 8 + (col >> 6)) * 64 + (col & 63)) * 512 + t] = pk;
      }
    }
  }
}

// ---------------- output projection ----------------
__global__ __launch_bounds__(256) void k_gemm_out(
    const short* __restrict__ AO, const short* __restrict__ Wob,
    const float* __restrict__ bo, float* __restrict__ out)
{
  __shared__ __align__(16) char smem[32768];
  const int m0 = blockIdx.x * 128;
  const int n0 = blockIdx.y * 128;
  f32x4 acc[4][4];
#pragma unroll
  for (int i = 0; i < 4; ++i)
#pragma unroll
    for (int j = 0; j < 4; ++j) acc[i][j] = {0.f, 0.f, 0.f, 0.f};
  gemm_mainloop(AO, Wob, m0, n0, smem, acc);

  const int lane = threadIdx.x & 63;
  const int wid = threadIdx.x >> 6;
  const int wm = wid >> 1, wn = wid & 1;
#pragma unroll
  for (int mi = 0; mi < 4; ++mi)
#pragma unroll
    for (int ni = 0; ni < 4; ++ni) {
      int col = n0 + wn * 64 + ni * 16 + (lane & 15);
      float bc = bo[col];
#pragma unroll
      for (int j = 0; j < 4; ++j) {
        int row = m0 + wm * 64 + mi * 16 + (lane >> 4) * 4 + j;
        out[(size_t)row * 512 + col] = acc[mi][ni][j] + bc;
      }
    }
}

// ---------------- flash attention v3: block per (b,h), K/V in LDS ----------
// (byte-identical to the fully-verified round-3 kernel)
// 8 waves x 64 q-rows. Swapped QK^T: S = mfma(K-frag, Q-frag) -> lane (g,x15)
// holds S[key=k0+16ki+4g+j][q=x15 within mi-tile]. Row reductions are in-lane
// + 2 shfl_xor(16,32). PV: P repacked (cvt_pk pairs) into per-wave swizzled
// LDS tile, read back as A-frag; V B-frags from LDS. O lands transposed
// (q=g*4+jj, dk=x15) -> per-row 1/l fetched by shfl at the end.
__global__ __launch_bounds__(512, 2) void k_attn(
    const short* __restrict__ Qb, const short* __restrict__ Kb, const short* __restrict__ Vt,
    const float* __restrict__ rel, const int* __restrict__ kpm,
    short* __restrict__ AO)
{
  const int bh = blockIdx.x;
  const int b = bh >> 3, h = bh & 7;
  const int tid = threadIdx.x;
  const int lane = tid & 63;
  const int w = tid >> 6;
  const int g = lane >> 4;
  const int x15 = lane & 15;

  __shared__ __align__(16) short s_k[32768];   // [512 rows][64] 16B-slot swizzled
  __shared__ __align__(16) short s_v[32768];   // [64 rows][512] slot swizzled
  __shared__ float s_rel[1024];
  __shared__ float s_km[512];
  __shared__ __align__(16) short s_p[8][1024]; // per-wave [16 q][64 k] swizzled

  // ---- stage K and V (64 KB each). LDS dest is WAVE-UNIFORM base (hardware
  // adds lane*16); the slot swizzle rides on the per-lane GLOBAL address.
#pragma unroll
  for (int it = 0; it < 8; ++it) {
    const int ub = it * 512 + w * 64;            // wave-uniform 16B-unit base
    const int u = ub + lane;                     // this lane's unit
    const int rk = u >> 3, sk = (u & 7) ^ (rk & 7);
    gll16(Kb + ((size_t)(b * 512 + rk)) * 512 + h * 64 + sk * 8,
          (char*)s_k + (size_t)ub * 16);
    const int rv = u >> 6, sv2 = (u & 63) ^ (rv & 7);
    gll16(Vt + ((size_t)((b * 8 + h) * 64 + rv)) * 512 + sv2 * 8,
          (char*)s_v + (size_t)ub * 16);
  }
  for (int i = tid; i < 1023; i += 512) s_rel[i] = rel[i * 8 + h];
  s_km[tid] = kpm[b * 512 + tid] ? NEG_BIG : 0.0f;

  // ---- Q fragments: wave w owns q rows w*64 .. +63 (4 tiles of 16)
  bf16x8 qf[4][2];
#pragma unroll
  for (int mi = 0; mi < 4; ++mi)
#pragma unroll
    for (int ks = 0; ks < 2; ++ks)
      qf[mi][ks] = *(const bf16x8*)(Qb + ((size_t)(b * 512 + w * 64 + mi * 16 + x15)) * 512
                                    + h * 64 + ks * 32 + g * 8);
  __syncthreads();

  float m_r[4], l_r[4];
  f32x4 acc[4][4];
#pragma unroll
  for (int mi = 0; mi < 4; ++mi) { m_r[mi] = NEG_BIG; l_r[mi] = 0.f; }
#pragma unroll
  for (int mi = 0; mi < 4; ++mi)
#pragma unroll
    for (int ni = 0; ni < 4; ++ni) acc[mi][ni] = {0.f, 0.f, 0.f, 0.f};

  for (int kt = 0; kt < 8; ++kt) {
    const int k0 = kt * 64;
    // K fragments from LDS
    bf16x8 kf[4][2];
#pragma unroll
    for (int ki = 0; ki < 4; ++ki)
#pragma unroll
      for (int ks = 0; ks < 2; ++ks) {
        int r = k0 + ki * 16 + x15;
        int p = (ks * 4 + g) ^ (x15 & 7);
        kf[ki][ks] = *(const bf16x8*)((const char*)s_k + r * 128 + p * 16);
      }
    // V fragments (mi-invariant)
    bf16x8 vf[2][4];
#pragma unroll
    for (int ks = 0; ks < 2; ++ks)
#pragma unroll
      for (int ni = 0; ni < 4; ++ni) {
        int r = ni * 16 + x15;
        int p = kt * 8 + ((ks * 4 + g) ^ (x15 & 7));
        vf[ks][ni] = *(const bf16x8*)((const char*)s_v + r * 1024 + p * 16);
      }
    // key mask values (mi-invariant; x15-invariant broadcast reads)
    float kmv[4][4];
#pragma unroll
    for (int ki = 0; ki < 4; ++ki)
#pragma unroll
      for (int j = 0; j < 4; ++j)
        kmv[ki][j] = s_km[k0 + ki * 16 + g * 4 + j];

    short* pw = s_p[w];
#pragma unroll
    for (int mi = 0; mi < 4; ++mi) {
      // S = K Q^T (keys on C-rows, q on C-cols): 8 MFMA
      f32x4 s[4];
#pragma unroll
      for (int ki = 0; ki < 4; ++ki) s[ki] = {0.f, 0.f, 0.f, 0.f};
#pragma unroll
      for (int ks = 0; ks < 2; ++ks)
#pragma unroll
        for (int ki = 0; ki < 4; ++ki)
          s[ki] = __builtin_amdgcn_mfma_f32_16x16x32_bf16(kf[ki][ks], qf[mi][ks], s[ki], 0, 0, 0);

      const int rbase = k0 + 511 - (w * 64 + mi * 16 + x15) + g * 4;
      float sv[4][4];
      float pmax = NEG_BIG;
#pragma unroll
      for (int ki = 0; ki < 4; ++ki)
#pragma unroll
        for (int j = 0; j < 4; ++j) {
          float v2 = s[ki][j] + s_rel[rbase + ki * 16 + j] + kmv[ki][j];
          sv[ki][j] = v2;
          pmax = fmaxf(pmax, v2);
        }
      // defer-max: skip reduce+rescale unless some lane exceeds m+8
      if (!__all(pmax - m_r[mi] <= 8.0f)) {
        float rm = fmaxf(pmax, __shfl_xor(pmax, 16, 64));
        rm = fmaxf(rm, __shfl_xor(rm, 32, 64));
        float mn = fmaxf(m_r[mi], rm);
        float sc = __expf(m_r[mi] - mn);
        l_r[mi] *= sc;
        m_r[mi] = mn;
        // rescale acc (O-layout rows q=g*4+jj need sc from lane x15=q; sc is
        // g-invariant so stay within the same 16-lane group)
        float scO[4];
#pragma unroll
        for (int jj = 0; jj < 4; ++jj)
          scO[jj] = __shfl(sc, (lane & 48) | (g * 4 + jj), 64);
#pragma unroll
        for (int ni = 0; ni < 4; ++ni)
#pragma unroll
          for (int jj = 0; jj < 4; ++jj) acc[mi][ni][jj] *= scO[jj];
      }
      float ps = 0.f;
      unsigned int pk[4][2];
#pragma unroll
      for (int ki = 0; ki < 4; ++ki) {
#pragma unroll
        for (int j = 0; j < 4; ++j) {
          float pe = __expf(sv[ki][j] - m_r[mi]);
          sv[ki][j] = pe;
          ps += pe;
        }
        pk[ki][0] = cvtpk(sv[ki][0], sv[ki][1]);
        pk[ki][1] = cvtpk(sv[ki][2], sv[ki][3]);
      }
      ps += __shfl_xor(ps, 16, 64);
      ps += __shfl_xor(ps, 32, 64);
      l_r[mi] += ps;
      // P -> per-wave swizzled LDS tile ([q=x15 row][key], 8B per ki)
#pragma unroll
      for (int ki = 0; ki < 4; ++ki) {
        int p = (2 * ki + (g >> 1)) ^ (x15 & 7);
        u32x2 pr; pr.x = pk[ki][0]; pr.y = pk[ki][1];
        *(u32x2*)((char*)pw + x15 * 128 + p * 16 + (g & 1) * 8) = pr;
      }
      // read back as A-frag, PV: 8 MFMA
      bf16x8 pf[2];
#pragma unroll
      for (int ks = 0; ks < 2; ++ks) {
        int p = (ks * 4 + g) ^ (x15 & 7);
        pf[ks] = *(const bf16x8*)((const char*)pw + x15 * 128 + p * 16);
      }
#pragma unroll
      for (int ks = 0; ks < 2; ++ks)
#pragma unroll
        for (int ni = 0; ni < 4; ++ni)
          acc[mi][ni] = __builtin_amdgcn_mfma_f32_16x16x32_bf16(pf[ks], vf[ks][ni], acc[mi][ni], 0, 0, 0);
    }
  }

  // ---- epilogue: O[q=g*4+jj][dk=x15+16ni], 1/l fetched from lane x15=q
#pragma unroll
  for (int mi = 0; mi < 4; ++mi) {
    float li = 1.0f / l_r[mi];
    float liO[4];
#pragma unroll
    for (int jj = 0; jj < 4; ++jj)
      liO[jj] = __shfl(li, (lane & 48) | (g * 4 + jj), 64);
#pragma unroll
    for (int ni = 0; ni < 4; ++ni)
#pragma unroll
      for (int jj = 0; jj < 4; ++jj) {
        int q = w * 64 + mi * 16 + g * 4 + jj;
        AO[((size_t)(b * 512 + q)) * 512 + h * 64 + ni * 16 + x15] =
            (short)f2b(acc[mi][ni][jj] * liO[jj]);
      }
  }
}

extern "C" void kernel_launch(void* const* d_in, const int* in_sizes, int n_in,
                              void* d_out, int out_size, void* d_ws, size_t ws_size,
                              hipStream_t stream) {
  const float* x   = (const float*)d_in[0];
  const float* Wq  = (const float*)d_in[1];
  const float* bq  = (const float*)d_in[2];
  const float* Wk  = (const float*)d_in[3];
  const float* bk  = (const float*)d_in[4];
  const float* Wv  = (const float*)d_in[5];
  const float* bv  = (const float*)d_in[6];
  const float* Wo  = (const float*)d_in[7];
  const float* bo  = (const float*)d_in[8];
  const float* rel = (const float*)d_in[9];
  const int*   kpm = (const int*)d_in[10];
  float* out = (float*)d_out;

  // ws layout (bf16 elements): xb[8M] wb[1M] Qb[8M] Kb[8M] Vt[8M] AO[8M]
  short* xb = (short*)d_ws;
  short* wb = xb + (size_t)8388608;
  short* Qb = wb + (size_t)1048576;
  short* Kb = Qb + (size_t)8388608;
  short* Vt = Kb + (size_t)8388608;
  short* AO = Vt + (size_t)8388608;

  k_cvt<<<9216, 256, 0, stream>>>(x, Wq, Wk, Wv, Wo, xb, wb);
  k_gemm_qkv<<<dim3(128, 12), 256, 0, stream>>>(xb, wb, bq, bk, bv, Qb, Kb, Vt);
  k_attn<<<256, 512, 0, stream>>>(Qb, Kb, Vt, rel, kpm, AO);
  k_gemm_out<<<dim3(128, 4), 256, 0, stream>>>(AO, wb + (size_t)3 * 262144, bo, out);
}

// Round 9
// 188.063 us; speedup vs baseline: 1.4936x; 1.0185x over previous
//
#include <hip/hip_runtime.h>
#include <cstdint>
#include <cstddef>
#include <cmath>

// RelPosMHA: x[32,512,512] f32 -> QKV proj -> rel-pos-bias attention -> out proj.
//  - k_cvt: f32 -> bf16 for x and Wq/Wk/Wv/Wo (byte-identical to green R8).
//  - k_gemm_qkv / k_gemm_out: bf16 MFMA GEMM, BK=64, single-buffered verified
//    sync template (STAGE; barrier; COMPUTE; barrier). R9: each block computes
//    TWO 128x128 C-tiles sharing one A-tile (128M x 256N span) -- staged bytes
//    drop 2.7x (786->295 MB through L2), compute-per-stall doubles. Same
//    barrier topology as the green R8 kernel (parameter-level change).
//  - k_attn v3: BYTE-IDENTICAL to the fully-green round-3/8 kernel.

typedef __attribute__((ext_vector_type(8))) short bf16x8;
typedef __attribute__((ext_vector_type(4))) float f32x4;
typedef __attribute__((ext_vector_type(4))) unsigned short u16x4;
typedef __attribute__((ext_vector_type(2))) unsigned int u32x2;

typedef __attribute__((address_space(3))) unsigned int lds_u32;
typedef const __attribute__((address_space(1))) unsigned int glb_u32;

#define NEG_BIG (-1.0e30f)

__device__ __forceinline__ unsigned short f2b(float f) {
  unsigned int u = __builtin_bit_cast(unsigned int, f);
  u += 0x7fffu + ((u >> 16) & 1u);   // RNE (no NaN inputs in this pipeline)
  return (unsigned short)(u >> 16);
}

__device__ __forceinline__ unsigned int cvtpk(float lo, float hi) {
  unsigned int r;
  asm("v_cvt_pk_bf16_f32 %0, %1, %2" : "=v"(r) : "v"(lo), "v"(hi));
  return r;
}

__device__ __forceinline__ void gll16(const void* g, void* l) {
  __builtin_amdgcn_global_load_lds((glb_u32*)g, (lds_u32*)l, 16, 0, 0);
}

// ---------------- convert f32 -> bf16 (x + 4 weights) ----------------
__global__ __launch_bounds__(256) void k_cvt(
    const float* __restrict__ x,
    const float* __restrict__ w0, const float* __restrict__ w1,
    const float* __restrict__ w2, const float* __restrict__ w3,
    short* __restrict__ xb, short* __restrict__ wb)
{
  size_t i = (size_t)blockIdx.x * 256 + threadIdx.x;
  size_t e = i * 4;
  const float* s;
  short* d;
  if (e < (size_t)8388608) { s = x + e; d = xb + e; }
  else {
    size_t r = e - 8388608;
    int ws = (int)(r >> 18);
    const float* wp = ws == 0 ? w0 : ws == 1 ? w1 : ws == 2 ? w2 : w3;
    s = wp + (r & 262143);
    d = wb + r;
  }
  f32x4 v = *(const f32x4*)s;
  u16x4 o;
  o.x = f2b(v.x); o.y = f2b(v.y); o.z = f2b(v.z); o.w = f2b(v.w);
  *(u16x4*)d = o;
}

// -- GEMM mainloop: two C[128x128] tiles (shared A) over a 256-col B span ----
// smem: A [128][64] at 0 (16 KB), B0 at +16384, B1 at +32768 (48 KB).
// 8 16B slots/row, LDS slot l of row r holds global slot l ^ (r&7); staged via
// global_load_lds w=16 with wave-uniform LDS base, swizzle on the per-lane
// GLOBAL address. Sync topology identical to the verified single-buffer
// template: STAGE-all; barrier; COMPUTE-all; barrier.
__device__ __forceinline__ void gemm_mainloop2(
    const short* __restrict__ A, const short* __restrict__ Bw,
    int m0, int n0, char* smem, f32x4 acc[2][4][4])
{
  const int tid = threadIdx.x;
  const int lane = tid & 63;
  const int wid = tid >> 6;
  const int wm = wid >> 1, wn = wid & 1;
  const int g = lane >> 4;
  const int x15 = lane & 15;
  char* smA = smem;
  char* smB0 = smem + 16384;
  char* smB1 = smem + 32768;

#pragma unroll 1
  for (int kk = 0; kk < 512; kk += 64) {
#pragma unroll
    for (int p = 0; p < 4; ++p) {
      int ub = p * 256 + wid * 64;          // wave-uniform 16B-unit base
      int u = ub + lane;
      int row = u >> 3;
      int gs = (u & 7) ^ (row & 7);
      gll16(A  + ((size_t)(m0 + row) * 512 + kk + gs * 8),       smA  + ub * 16);
      gll16(Bw + ((size_t)(n0 + row) * 512 + kk + gs * 8),       smB0 + ub * 16);
      gll16(Bw + ((size_t)(n0 + 128 + row) * 512 + kk + gs * 8), smB1 + ub * 16);
    }
    __syncthreads();                        // vmcnt drained: tiles visible
    bf16x8 av[4][2];
#pragma unroll
    for (int mi = 0; mi < 4; ++mi)
#pragma unroll
      for (int ks = 0; ks < 2; ++ks) {
        int r = wm * 64 + mi * 16 + x15;
        int sl = (ks * 4 + g) ^ (x15 & 7);
        av[mi][ks] = *(const bf16x8*)(smA + r * 128 + sl * 16);
      }
#pragma unroll
    for (int t = 0; t < 2; ++t) {
      char* smB = t == 0 ? smB0 : smB1;
      bf16x8 bv[4][2];
#pragma unroll
      for (int ni = 0; ni < 4; ++ni)
#pragma unroll
        for (int ks = 0; ks < 2; ++ks) {
          int r = wn * 64 + ni * 16 + x15;
          int sl = (ks * 4 + g) ^ (x15 & 7);
          bv[ni][ks] = *(const bf16x8*)(smB + r * 128 + sl * 16);
        }
#pragma unroll
      for (int ks = 0; ks < 2; ++ks)
#pragma unroll
        for (int mi = 0; mi < 4; ++mi)
#pragma unroll
          for (int ni = 0; ni < 4; ++ni)
            acc[t][mi][ni] = __builtin_amdgcn_mfma_f32_16x16x32_bf16(av[mi][ks], bv[ni][ks], acc[t][mi][ni], 0, 0, 0);
    }
    __syncthreads();                        // reads done before next stage
  }
}

// ---------------- QKV projection (fused Q,K,V) ----------------
// grid: (128 m-blocks, 6): y -> sel = y>>1 (0=Q 1=K 2=V), n0 = (y&1)*256.
__global__ __launch_bounds__(256, 2) void k_gemm_qkv(
    const short* __restrict__ xb, const short* __restrict__ wb,
    const float* __restrict__ bq, const float* __restrict__ bk, const float* __restrict__ bv,
    short* __restrict__ Qb, short* __restrict__ Kb, short* __restrict__ Vt)
{
  __shared__ __align__(16) char smem[49152];
  const int m0 = blockIdx.x * 128;
  const int nb = blockIdx.y;
  const int sel = nb >> 1;             // 0=Q 1=K 2=V
  const int n0 = (nb & 1) * 256;
  const short* Bw = wb + (size_t)sel * 262144;
  const float* bias = sel == 0 ? bq : (sel == 1 ? bk : bv);

  f32x4 acc[2][4][4];
#pragma unroll
  for (int t = 0; t < 2; ++t)
#pragma unroll
    for (int i = 0; i < 4; ++i)
#pragma unroll
      for (int j = 0; j < 4; ++j) acc[t][i][j] = {0.f, 0.f, 0.f, 0.f};
  gemm_mainloop2(xb, Bw, m0, n0, smem, acc);

  const int lane = threadIdx.x & 63;
  const int wid = threadIdx.x >> 6;
  const int wm = wid >> 1, wn = wid & 1;
  const float scale = sel == 0 ? 0.125f : 1.0f;   // fold 1/sqrt(DK) into Q

  if (sel < 2) {
    short* O = sel == 0 ? Qb : Kb;
#pragma unroll
    for (int t = 0; t < 2; ++t)
#pragma unroll
      for (int mi = 0; mi < 4; ++mi)
#pragma unroll
        for (int ni = 0; ni < 4; ++ni) {
          int col = n0 + t * 128 + wn * 64 + ni * 16 + (lane & 15);
          float bc = bias[col];
#pragma unroll
          for (int j = 0; j < 4; ++j) {
            int row = m0 + wm * 64 + mi * 16 + (lane >> 4) * 4 + j;
            O[(size_t)row * 512 + col] = (short)f2b((acc[t][mi][ni][j] + bc) * scale);
          }
        }
  } else {
#pragma unroll
    for (int t = 0; t < 2; ++t)
#pragma unroll
      for (int mi = 0; mi < 4; ++mi) {
        int rowb = m0 + wm * 64 + mi * 16 + (lane >> 4) * 4;
        int bidx = rowb >> 9;
        int tr = rowb & 511;
#pragma unroll
        for (int ni = 0; ni < 4; ++ni) {
          int col = n0 + t * 128 + wn * 64 + ni * 16 + (lane & 15);
          float bc = bias[col];
          u16x4 pk;
#pragma unroll
          for (int j = 0; j < 4; ++j) pk[j] = f2b(acc[t][mi][ni][j] + bc);
          *(u16x4*)&Vt[(((size_t)bidx * 8 + (col >> 6)) * 64 + (col & 63)) * 512 + tr] = pk;
        }
      }
  }
}

// ---------------- output projection ----------------
// grid: (128 m-blocks, 2): n0 = y*256.
__global__ __launch_bounds__(256, 2) void k_gemm_out(
    const short* __restrict__ AO, const short* __restrict__ Wob,
    const float* __restrict__ bo, float* __restrict__ out)
{
  __shared__ __align__(16) char smem[49152];
  const int m0 = blockIdx.x * 128;
  const int n0 = blockIdx.y * 256;
  f32x4 acc[2][4][4];
#pragma unroll
  for (int t = 0; t < 2; ++t)
#pragma unroll
    for (int i = 0; i < 4; ++i)
#pragma unroll
      for (int j = 0; j < 4; ++j) acc[t][i][j] = {0.f, 0.f, 0.f, 0.f};
  gemm_mainloop2(AO, Wob, m0, n0, smem, acc);

  const int lane = threadIdx.x & 63;
  const int wid = threadIdx.x >> 6;
  const int wm = wid >> 1, wn = wid & 1;
#pragma unroll
  for (int t = 0; t < 2; ++t)
#pragma unroll
    for (int mi = 0; mi < 4; ++mi)
#pragma unroll
      for (int ni = 0; ni < 4; ++ni) {
        int col = n0 + t * 128 + wn * 64 + ni * 16 + (lane & 15);
        float bc = bo[col];
#pragma unroll
        for (int j = 0; j < 4; ++j) {
          int row = m0 + wm * 64 + mi * 16 + (lane >> 4) * 4 + j;
          out[(size_t)row * 512 + col] = acc[t][mi][ni][j] + bc;
        }
      }
}

// ---------------- flash attention v3: block per (b,h), K/V in LDS ----------
// (byte-identical to the fully-verified round-3/8 kernel)
__global__ __launch_bounds__(512, 2) void k_attn(
    const short* __restrict__ Qb, const short* __restrict__ Kb, const short* __restrict__ Vt,
    const float* __restrict__ rel, const int* __restrict__ kpm,
    short* __restrict__ AO)
{
  const int bh = blockIdx.x;
  const int b = bh >> 3, h = bh & 7;
  const int tid = threadIdx.x;
  const int lane = tid & 63;
  const int w = tid >> 6;
  const int g = lane >> 4;
  const int x15 = lane & 15;

  __shared__ __align__(16) short s_k[32768];   // [512 rows][64] 16B-slot swizzled
  __shared__ __align__(16) short s_v[32768];   // [64 rows][512] slot swizzled
  __shared__ float s_rel[1024];
  __shared__ float s_km[512];
  __shared__ __align__(16) short s_p[8][1024]; // per-wave [16 q][64 k] swizzled

  // ---- stage K and V (64 KB each). LDS dest is WAVE-UNIFORM base (hardware
  // adds lane*16); the slot swizzle rides on the per-lane GLOBAL address.
#pragma unroll
  for (int it = 0; it < 8; ++it) {
    const int ub = it * 512 + w * 64;            // wave-uniform 16B-unit base
    const int u = ub + lane;                     // this lane's unit
    const int rk = u >> 3, sk = (u & 7) ^ (rk & 7);
    gll16(Kb + ((size_t)(b * 512 + rk)) * 512 + h * 64 + sk * 8,
          (char*)s_k + (size_t)ub * 16);
    const int rv = u >> 6, sv2 = (u & 63) ^ (rv & 7);
    gll16(Vt + ((size_t)((b * 8 + h) * 64 + rv)) * 512 + sv2 * 8,
          (char*)s_v + (size_t)ub * 16);
  }
  for (int i = tid; i < 1023; i += 512) s_rel[i] = rel[i * 8 + h];
  s_km[tid] = kpm[b * 512 + tid] ? NEG_BIG : 0.0f;

  // ---- Q fragments: wave w owns q rows w*64 .. +63 (4 tiles of 16)
  bf16x8 qf[4][2];
#pragma unroll
  for (int mi = 0; mi < 4; ++mi)
#pragma unroll
    for (int ks = 0; ks < 2; ++ks)
      qf[mi][ks] = *(const bf16x8*)(Qb + ((size_t)(b * 512 + w * 64 + mi * 16 + x15)) * 512
                                    + h * 64 + ks * 32 + g * 8);
  __syncthreads();

  float m_r[4], l_r[4];
  f32x4 acc[4][4];
#pragma unroll
  for (int mi = 0; mi < 4; ++mi) { m_r[mi] = NEG_BIG; l_r[mi] = 0.f; }
#pragma unroll
  for (int mi = 0; mi < 4; ++mi)
#pragma unroll
    for (int ni = 0; ni < 4; ++ni) acc[mi][ni] = {0.f, 0.f, 0.f, 0.f};

  for (int kt = 0; kt < 8; ++kt) {
    const int k0 = kt * 64;
    // K fragments from LDS
    bf16x8 kf[4][2];
#pragma unroll
    for (int ki = 0; ki < 4; ++ki)
#pragma unroll
      for (int ks = 0; ks < 2; ++ks) {
        int r = k0 + ki * 16 + x15;
        int p = (ks * 4 + g) ^ (x15 & 7);
        kf[ki][ks] = *(const bf16x8*)((const char*)s_k + r * 128 + p * 16);
      }
    // V fragments (mi-invariant)
    bf16x8 vf[2][4];
#pragma unroll
    for (int ks = 0; ks < 2; ++ks)
#pragma unroll
      for (int ni = 0; ni < 4; ++ni) {
        int r = ni * 16 + x15;
        int p = kt * 8 + ((ks * 4 + g) ^ (x15 & 7));
        vf[ks][ni] = *(const bf16x8*)((const char*)s_v + r * 1024 + p * 16);
      }
    // key mask values (mi-invariant; x15-invariant broadcast reads)
    float kmv[4][4];
#pragma unroll
    for (int ki = 0; ki < 4; ++ki)
#pragma unroll
      for (int j = 0; j < 4; ++j)
        kmv[ki][j] = s_km[k0 + ki * 16 + g * 4 + j];

    short* pw = s_p[w];
#pragma unroll
    for (int mi = 0; mi < 4; ++mi) {
      // S = K Q^T (keys on C-rows, q on C-cols): 8 MFMA
      f32x4 s[4];
#pragma unroll
      for (int ki = 0; ki < 4; ++ki) s[ki] = {0.f, 0.f, 0.f, 0.f};
#pragma unroll
      for (int ks = 0; ks < 2; ++ks)
#pragma unroll
        for (int ki = 0; ki < 4; ++ki)
          s[ki] = __builtin_amdgcn_mfma_f32_16x16x32_bf16(kf[ki][ks], qf[mi][ks], s[ki], 0, 0, 0);

      const int rbase = k0 + 511 - (w * 64 + mi * 16 + x15) + g * 4;
      float sv[4][4];
      float pmax = NEG_BIG;
#pragma unroll
      for (int ki = 0; ki < 4; ++ki)
#pragma unroll
        for (int j = 0; j < 4; ++j) {
          float v2 = s[ki][j] + s_rel[rbase + ki * 16 + j] + kmv[ki][j];
          sv[ki][j] = v2;
          pmax = fmaxf(pmax, v2);
        }
      // defer-max: skip reduce+rescale unless some lane exceeds m+8
      if (!__all(pmax - m_r[mi] <= 8.0f)) {
        float rm = fmaxf(pmax, __shfl_xor(pmax, 16, 64));
        rm = fmaxf(rm, __shfl_xor(rm, 32, 64));
        float mn = fmaxf(m_r[mi], rm);
        float sc = __expf(m_r[mi] - mn);
        l_r[mi] *= sc;
        m_r[mi] = mn;
        // rescale acc (O-layout rows q=g*4+jj need sc from lane x15=q; sc is
        // g-invariant so stay within the same 16-lane group)
        float scO[4];
#pragma unroll
        for (int jj = 0; jj < 4; ++jj)
          scO[jj] = __shfl(sc, (lane & 48) | (g * 4 + jj), 64);
#pragma unroll
        for (int ni = 0; ni < 4; ++ni)
#pragma unroll
          for (int jj = 0; jj < 4; ++jj) acc[mi][ni][jj] *= scO[jj];
      }
      float ps = 0.f;
      unsigned int pk[4][2];
#pragma unroll
      for (int ki = 0; ki < 4; ++ki) {
#pragma unroll
        for (int j = 0; j < 4; ++j) {
          float pe = __expf(sv[ki][j] - m_r[mi]);
          sv[ki][j] = pe;
          ps += pe;
        }
        pk[ki][0] = cvtpk(sv[ki][0], sv[ki][1]);
        pk[ki][1] = cvtpk(sv[ki][2], sv[ki][3]);
      }
      ps += __shfl_xor(ps, 16, 64);
      ps += __shfl_xor(ps, 32, 64);
      l_r[mi] += ps;
      // P -> per-wave swizzled LDS tile ([q=x15 row][key], 8B per ki)
#pragma unroll
      for (int ki = 0; ki < 4; ++ki) {
        int p = (2 * ki + (g >> 1)) ^ (x15 & 7);
        u32x2 pr; pr.x = pk[ki][0]; pr.y = pk[ki][1];
        *(u32x2*)((char*)pw + x15 * 128 + p * 16 + (g & 1) * 8) = pr;
      }
      // read back as A-frag, PV: 8 MFMA
      bf16x8 pf[2];
#pragma unroll
      for (int ks = 0; ks < 2; ++ks) {
        int p = (ks * 4 + g) ^ (x15 & 7);
        pf[ks] = *(const bf16x8*)((const char*)pw + x15 * 128 + p * 16);
      }
#pragma unroll
      for (int ks = 0; ks < 2; ++ks)
#pragma unroll
        for (int ni = 0; ni < 4; ++ni)
          acc[mi][ni] = __builtin_amdgcn_mfma_f32_16x16x32_bf16(pf[ks], vf[ks][ni], acc[mi][ni], 0, 0, 0);
    }
  }

  // ---- epilogue: O[q=g*4+jj][dk=x15+16ni], 1/l fetched from lane x15=q
#pragma unroll
  for (int mi = 0; mi < 4; ++mi) {
    float li = 1.0f / l_r[mi];
    float liO[4];
#pragma unroll
    for (int jj = 0; jj < 4; ++jj)
      liO[jj] = __shfl(li, (lane & 48) | (g * 4 + jj), 64);
#pragma unroll
    for (int ni = 0; ni < 4; ++ni)
#pragma unroll
      for (int jj = 0; jj < 4; ++jj) {
        int q = w * 64 + mi * 16 + g * 4 + jj;
        AO[((size_t)(b * 512 + q)) * 512 + h * 64 + ni * 16 + x15] =
            (short)f2b(acc[mi][ni][jj] * liO[jj]);
      }
  }
}

extern "C" void kernel_launch(void* const* d_in, const int* in_sizes, int n_in,
                              void* d_out, int out_size, void* d_ws, size_t ws_size,
                              hipStream_t stream) {
  const float* x   = (const float*)d_in[0];
  const float* Wq  = (const float*)d_in[1];
  const float* bq  = (const float*)d_in[2];
  const float* Wk  = (const float*)d_in[3];
  const float* bk  = (const float*)d_in[4];
  const float* Wv  = (const float*)d_in[5];
  const float* bv  = (const float*)d_in[6];
  const float* Wo  = (const float*)d_in[7];
  const float* bo  = (const float*)d_in[8];
  const float* rel = (const float*)d_in[9];
  const int*   kpm = (const int*)d_in[10];
  float* out = (float*)d_out;

  // ws layout (bf16 elements): xb[8M] wb[1M] Qb[8M] Kb[8M] Vt[8M] AO[8M]
  short* xb = (short*)d_ws;
  short* wb = xb + (size_t)8388608;
  short* Qb = wb + (size_t)1048576;
  short* Kb = Qb + (size_t)8388608;
  short* Vt = Kb + (size_t)8388608;
  short* AO = Vt + (size_t)8388608;

  k_cvt<<<9216, 256, 0, stream>>>(x, Wq, Wk, Wv, Wo, xb, wb);
  k_gemm_qkv<<<dim3(128, 6), 256, 0, stream>>>(xb, wb, bq, bk, bv, Qb, Kb, Vt);
  k_attn<<<256, 512, 0, stream>>>(Qb, Kb, Vt, rel, kpm, AO);
  k_gemm_out<<<dim3(128, 2), 256, 0, stream>>>(AO, wb + (size_t)3 * 262144, bo, out);
}